// Round 2
// baseline (494.204 us; speedup 1.0000x reference)
//
#include <hip/hip_runtime.h>
#include <hip/hip_bf16.h>
#include <cstdint>

#define BB 4
#define LL 2048
#define DD 256
#define HH 8
#define HDIM 32
#define MTOT (BB * LL)          // 8192
#define BHT (BB * HH)           // 32
#define ROWS ((size_t)BHT * LL) // 65536

static constexpr float SCALE = 0.17677669529663687f;  // 1/sqrt(32)

// ---------------------------------------------------------------------------
// GEMM: C = A @ W^T + bias.  A:[M=8192, K=256] row-major, W:[N=256, K=256].
// MODE 0: store C[m*256 + n]                (final projection -> d_out)
// MODE 1: scatter to [B, H, L, HD] layout   (q/k/v for attention)
// Tile: 64x64 output per block, BK=16, 256 threads, 4x4 micro-tile/thread.
// ---------------------------------------------------------------------------
template <int MODE>
__global__ __launch_bounds__(256) void gemm_xwT(const float* __restrict__ A,
                                                const float* __restrict__ W,
                                                const float* __restrict__ bias,
                                                float* __restrict__ C) {
    __shared__ float As[16][68];  // [k][m], +4 pad keeps float4 alignment, breaks bank stride
    __shared__ float Bs[16][68];  // [k][n]
    const int tid = threadIdx.x;
    const int tx = tid & 15;   // n direction (4 cols each)
    const int ty = tid >> 4;   // m direction (4 rows each)
    const int bm = blockIdx.x * 64;
    const int bn = blockIdx.y * 64;
    const int lk = tid & 15;   // k lane for staging
    const int lr = tid >> 4;   // row group for staging

    float acc[4][4] = {};

    for (int k0 = 0; k0 < DD; k0 += 16) {
#pragma unroll
        for (int i = 0; i < 4; ++i) {
            const int m = lr + i * 16;
            As[lk][m] = A[(size_t)(bm + m) * DD + k0 + lk];
            Bs[lk][m] = W[(size_t)(bn + m) * DD + k0 + lk];
        }
        __syncthreads();
#pragma unroll
        for (int k = 0; k < 16; ++k) {
            const float4 av = *(const float4*)&As[k][ty * 4];
            const float4 bv = *(const float4*)&Bs[k][tx * 4];
            const float a_[4] = {av.x, av.y, av.z, av.w};
            const float b_[4] = {bv.x, bv.y, bv.z, bv.w};
#pragma unroll
            for (int i = 0; i < 4; ++i)
#pragma unroll
                for (int j = 0; j < 4; ++j)
                    acc[i][j] = fmaf(a_[i], b_[j], acc[i][j]);
        }
        __syncthreads();
    }

#pragma unroll
    for (int i = 0; i < 4; ++i) {
        const int m = bm + ty * 4 + i;
#pragma unroll
        for (int j = 0; j < 4; ++j) {
            const int n = bn + tx * 4 + j;
            const float v = acc[i][j] + bias[n];
            if (MODE == 0) {
                C[(size_t)m * DD + n] = v;
            } else {
                const int b_ = m >> 11;          // m / L
                const int l_ = m & (LL - 1);     // m % L
                const int h_ = n >> 5;           // n / HD
                const int hd_ = n & (HDIM - 1);  // n % HD
                C[(((size_t)b_ * HH + h_) * LL + l_) * HDIM + hd_] = v;
            }
        }
    }
}

// ---------------------------------------------------------------------------
// Shared inner body for causal flash attention, fp32.
// One wave (64 threads), one query row per lane, K/V staged 32x32 in LDS.
// ---------------------------------------------------------------------------
__device__ __forceinline__ void attn_tile_update(
    const float* __restrict__ K, const float* __restrict__ V,
    float Ks[32][32], float Vs[32][32],
    int bh, int kt, int r, int tid,
    const float q[HDIM], float acc[HDIM], float& mrun, float& lrun) {
    // Cooperative stage of K/V 32x32 tiles (coalesced float4).
    const float4* ksrc = (const float4*)(K + ((size_t)bh * LL + kt) * HDIM);
    const float4* vsrc = (const float4*)(V + ((size_t)bh * LL + kt) * HDIM);
    float4* kd = (float4*)&Ks[0][0];
    float4* vd = (float4*)&Vs[0][0];
#pragma unroll
    for (int i = 0; i < 4; ++i) {
        kd[i * 64 + tid] = ksrc[i * 64 + tid];
        vd[i * 64 + tid] = vsrc[i * 64 + tid];
    }
    __syncthreads();

    if (kt <= r) {  // this row has at least one valid key in the tile
        float s[32];
#pragma unroll
        for (int j = 0; j < 32; ++j) {
            float sc = 0.f;
#pragma unroll
            for (int d4 = 0; d4 < 8; ++d4) {
                const float4 kv = *(const float4*)&Ks[j][d4 * 4];
                sc = fmaf(q[d4 * 4 + 0], kv.x, sc);
                sc = fmaf(q[d4 * 4 + 1], kv.y, sc);
                sc = fmaf(q[d4 * 4 + 2], kv.z, sc);
                sc = fmaf(q[d4 * 4 + 3], kv.w, sc);
            }
            s[j] = (kt + j <= r) ? sc * SCALE : -1e30f;  // causal mask
        }
        float pmax = s[0];
#pragma unroll
        for (int j = 1; j < 32; ++j) pmax = fmaxf(pmax, s[j]);
        const float mnew = fmaxf(mrun, pmax);
        const float corr = __expf(mrun - mnew);
        float psum = 0.f;
#pragma unroll
        for (int j = 0; j < 32; ++j) {
            s[j] = __expf(s[j] - mnew);  // masked entries underflow to 0
            psum += s[j];
        }
        lrun = lrun * corr + psum;
        mrun = mnew;
#pragma unroll
        for (int d = 0; d < HDIM; ++d) acc[d] *= corr;
#pragma unroll
        for (int j = 0; j < 32; ++j) {
            const float p = s[j];
#pragma unroll
            for (int d4 = 0; d4 < 8; ++d4) {
                const float4 vv = *(const float4*)&Vs[j][d4 * 4];
                acc[d4 * 4 + 0] = fmaf(p, vv.x, acc[d4 * 4 + 0]);
                acc[d4 * 4 + 1] = fmaf(p, vv.y, acc[d4 * 4 + 1]);
                acc[d4 * 4 + 2] = fmaf(p, vv.z, acc[d4 * 4 + 2]);
                acc[d4 * 4 + 3] = fmaf(p, vv.w, acc[d4 * 4 + 3]);
            }
        }
    }
    __syncthreads();
}

__device__ __forceinline__ void load_q(const float* __restrict__ Q, int bh, int r,
                                       float q[HDIM]) {
    const float* qptr = Q + ((size_t)bh * LL + r) * HDIM;
#pragma unroll
    for (int i = 0; i < 8; ++i) {
        const float4 t = *(const float4*)(qptr + i * 4);
        q[i * 4 + 0] = t.x; q[i * 4 + 1] = t.y;
        q[i * 4 + 2] = t.z; q[i * 4 + 3] = t.w;
    }
}

// ---------------------------------------------------------------------------
// Split-K causal flash attention. Grid: (L/64, BH, S). blockIdx.z picks a
// contiguous chunk of the causal key range; partials (m, l, unnormalized acc)
// go to workspace and a merge kernel combines them.
// ---------------------------------------------------------------------------
__global__ __launch_bounds__(64) void attn_fwd_split(const float* __restrict__ Q,
                                                     const float* __restrict__ K,
                                                     const float* __restrict__ V,
                                                     float* __restrict__ pacc,
                                                     float* __restrict__ pml,
                                                     int S) {
    __shared__ float Ks[32][32];
    __shared__ float Vs[32][32];
    const int tid = threadIdx.x;
    const int qt = (gridDim.x - 1) - blockIdx.x;  // longest-first dispatch
    const int bh = blockIdx.y;
    const int sp = blockIdx.z;
    const int r = qt * 64 + tid;

    const int ntiles = (qt + 1) * 2;              // 32-key tiles in causal range
    const int T = (ntiles + S - 1) / S;
    const int t0 = sp * T;
    const int t1 = min(t0 + T, ntiles);

    float q[HDIM];
    load_q(Q, bh, r, q);

    float acc[HDIM] = {};
    float mrun = -1e30f;
    float lrun = 0.f;

    for (int t = t0; t < t1; ++t)
        attn_tile_update(K, V, Ks, Vs, bh, t * 32, r, tid, q, acc, mrun, lrun);

    // Write partials (empty splits / fully-masked lanes write m=-1e30, l=0, acc=0).
    const size_t row = ((size_t)sp * BHT + bh) * LL + r;
    pml[row * 2 + 0] = mrun;
    pml[row * 2 + 1] = lrun;
    float4* pa = (float4*)(pacc + row * HDIM);
#pragma unroll
    for (int i = 0; i < 8; ++i) {
        float4 o;
        o.x = acc[i * 4 + 0]; o.y = acc[i * 4 + 1];
        o.z = acc[i * 4 + 2]; o.w = acc[i * 4 + 3];
        pa[i] = o;
    }
}

// Merge S partials per row -> normalized output in [B, L, D] layout.
__global__ __launch_bounds__(256) void attn_merge(const float* __restrict__ pacc,
                                                  const float* __restrict__ pml,
                                                  float* __restrict__ Y, int S) {
    const int idx = blockIdx.x * 256 + threadIdx.x;  // over BH*L rows
    const int bh = idx >> 11;       // / L
    const int r = idx & (LL - 1);   // % L

    float M = -1e30f;
    for (int s = 0; s < S; ++s) {
        const size_t row = ((size_t)s * BHT + bh) * LL + r;
        M = fmaxf(M, pml[row * 2 + 0]);
    }
    float Lt = 0.f;
    float acc[HDIM] = {};
    for (int s = 0; s < S; ++s) {
        const size_t row = ((size_t)s * BHT + bh) * LL + r;
        const float m = pml[row * 2 + 0];
        const float l = pml[row * 2 + 1];
        const float w = __expf(m - M);  // 0 for empty splits
        Lt += l * w;
        const float4* pa = (const float4*)(pacc + row * HDIM);
#pragma unroll
        for (int i = 0; i < 8; ++i) {
            const float4 t = pa[i];
            acc[i * 4 + 0] = fmaf(w, t.x, acc[i * 4 + 0]);
            acc[i * 4 + 1] = fmaf(w, t.y, acc[i * 4 + 1]);
            acc[i * 4 + 2] = fmaf(w, t.z, acc[i * 4 + 2]);
            acc[i * 4 + 3] = fmaf(w, t.w, acc[i * 4 + 3]);
        }
    }
    const float inv = 1.f / Lt;
    float* yrow = Y + ((size_t)(bh >> 3) * LL + r) * DD + (bh & 7) * HDIM;
#pragma unroll
    for (int i = 0; i < 8; ++i) {
        float4 o;
        o.x = acc[i * 4 + 0] * inv;
        o.y = acc[i * 4 + 1] * inv;
        o.z = acc[i * 4 + 2] * inv;
        o.w = acc[i * 4 + 3] * inv;
        *(float4*)(yrow + i * 4) = o;
    }
}

// ---------------------------------------------------------------------------
// Direct (no-split) fallback: normalized output straight to [B, L, D].
// ---------------------------------------------------------------------------
__global__ __launch_bounds__(64) void attn_fwd(const float* __restrict__ Q,
                                               const float* __restrict__ K,
                                               const float* __restrict__ V,
                                               float* __restrict__ Y) {
    __shared__ float Ks[32][32];
    __shared__ float Vs[32][32];
    const int tid = threadIdx.x;
    const int qt = (gridDim.x - 1) - blockIdx.x;  // longest-first dispatch
    const int bh = blockIdx.y;
    const int r = qt * 64 + tid;

    float q[HDIM];
    load_q(Q, bh, r, q);

    float acc[HDIM] = {};
    float mrun = -1e30f;
    float lrun = 0.f;

    const int nt = (qt + 1) * 2;
    for (int t = 0; t < nt; ++t)
        attn_tile_update(K, V, Ks, Vs, bh, t * 32, r, tid, q, acc, mrun, lrun);

    const float inv = 1.f / lrun;
    float* yrow = Y + ((size_t)(bh >> 3) * LL + r) * DD + (bh & 7) * HDIM;
#pragma unroll
    for (int i = 0; i < 8; ++i) {
        float4 o;
        o.x = acc[i * 4 + 0] * inv;
        o.y = acc[i * 4 + 1] * inv;
        o.z = acc[i * 4 + 2] * inv;
        o.w = acc[i * 4 + 3] * inv;
        *(float4*)(yrow + i * 4) = o;
    }
}

// ---------------------------------------------------------------------------
extern "C" void kernel_launch(void* const* d_in, const int* in_sizes, int n_in,
                              void* d_out, int out_size, void* d_ws, size_t ws_size,
                              hipStream_t stream) {
    const float* key   = (const float*)d_in[0];
    const float* value = (const float*)d_in[1];
    const float* query = (const float*)d_in[2];
    const float* Wk = (const float*)d_in[3];
    const float* bk = (const float*)d_in[4];
    const float* Wq = (const float*)d_in[5];
    const float* bq = (const float*)d_in[6];
    const float* Wv = (const float*)d_in[7];
    const float* bv = (const float*)d_in[8];
    const float* Wp = (const float*)d_in[9];
    const float* bp = (const float*)d_in[10];
    float* out = (float*)d_out;
    float* ws = (float*)d_ws;

    const size_t SZ = (size_t)BB * HH * LL * HDIM;   // 2,097,152 floats per tensor
    const size_t BLD = (size_t)BB * LL * DD;         // 2,097,152 floats
    float* qb = ws;            // [B,H,L,HD]
    float* kb = ws + SZ;       // [B,H,L,HD]
    float* vb = ws + 2 * SZ;   // [B,H,L,HD]
    float* yb = ws + 3 * SZ;   // [B,L,D]
    float* pbase = ws + 3 * SZ + BLD;

    // Pick split factor by workspace budget: need (4*SZ + S*ROWS*34) floats.
    int S = 0;
    if (ws_size >= (4 * SZ + 4 * ROWS * 34) * sizeof(float)) S = 4;
    else if (ws_size >= (4 * SZ + 2 * ROWS * 34) * sizeof(float)) S = 2;

    const dim3 gg(MTOT / 64, DD / 64);
    const dim3 gb(256);
    gemm_xwT<1><<<gg, gb, 0, stream>>>(query, Wq, bq, qb);
    gemm_xwT<1><<<gg, gb, 0, stream>>>(key,   Wk, bk, kb);
    gemm_xwT<1><<<gg, gb, 0, stream>>>(value, Wv, bv, vb);

    if (S > 0) {
        float* pml = pbase;                          // [S, BH, L, 2]
        float* pacc = pbase + (size_t)S * ROWS * 2;  // [S, BH, L, 32]
        attn_fwd_split<<<dim3(LL / 64, BHT, S), 64, 0, stream>>>(qb, kb, vb, pacc, pml, S);
        attn_merge<<<dim3((int)(ROWS / 256)), 256, 0, stream>>>(pacc, pml, yb, S);
    } else {
        attn_fwd<<<dim3(LL / 64, BHT), 64, 0, stream>>>(qb, kb, vb, yb);
    }

    gemm_xwT<0><<<gg, gb, 0, stream>>>(yb, Wp, bp, out);
}

// Round 5
// 251.171 us; speedup vs baseline: 1.9676x; 1.9676x over previous
//
#include <hip/hip_runtime.h>
#include <hip/hip_bf16.h>
#include <cstdint>

#define BB 4
#define LL 2048
#define DD 256
#define HH 8
#define HDIM 32
#define MTOT (BB * LL)          // 8192
#define BHT (BB * HH)           // 32

typedef __attribute__((ext_vector_type(8))) short short8;   // 8 bf16 = 4 VGPRs
typedef __attribute__((ext_vector_type(4))) float f32x4;

static constexpr float SCALE = 0.17677669529663687f;  // 1/sqrt(32)

// float -> bf16 bits, round-to-nearest-even (finite inputs only)
__device__ __forceinline__ unsigned f2bf(float f) {
    const unsigned u = __builtin_bit_cast(unsigned, f);
    return (u + 0x7fffu + ((u >> 16) & 1u)) >> 16;
}

// ---------------------------------------------------------------------------
// GEMM: C = A @ W^T + bias.  A:[M=8192, K=256] f32 row-major, W:[N=256, K=256].
// MODE 0: f32 out [M,256]                       (final projection -> d_out)
// MODE 1: bf16, scaled by 1/sqrt(HD), [B,H,L,32] (Q)
// MODE 2: bf16, [B,H,L,32]                       (K)
// MODE 3: bf16 transposed, [B,H,32,L]            (V^T)
// ---------------------------------------------------------------------------
template <int MODE>
__global__ __launch_bounds__(256) void gemm_xwT(const float* __restrict__ A,
                                                const float* __restrict__ W,
                                                const float* __restrict__ bias,
                                                void* __restrict__ Cout) {
    __shared__ float As[16][68];  // [k][m]
    __shared__ float Bs[16][68];  // [k][n]
    const int tid = threadIdx.x;
    const int tx = tid & 15;   // n direction (4 cols each)
    const int ty = tid >> 4;   // m direction (4 rows each)
    const int bm = blockIdx.x * 64;
    const int bn = blockIdx.y * 64;
    const int lk = tid & 15;
    const int lr = tid >> 4;

    float acc[4][4] = {};

    for (int k0 = 0; k0 < DD; k0 += 16) {
#pragma unroll
        for (int i = 0; i < 4; ++i) {
            const int m = lr + i * 16;
            As[lk][m] = A[(size_t)(bm + m) * DD + k0 + lk];
            Bs[lk][m] = W[(size_t)(bn + m) * DD + k0 + lk];
        }
        __syncthreads();
#pragma unroll
        for (int k = 0; k < 16; ++k) {
            const float4 av = *(const float4*)&As[k][ty * 4];
            const float4 bv = *(const float4*)&Bs[k][tx * 4];
            const float a_[4] = {av.x, av.y, av.z, av.w};
            const float b_[4] = {bv.x, bv.y, bv.z, bv.w};
#pragma unroll
            for (int i = 0; i < 4; ++i)
#pragma unroll
                for (int j = 0; j < 4; ++j)
                    acc[i][j] = fmaf(a_[i], b_[j], acc[i][j]);
        }
        __syncthreads();
    }

    const int m0 = bm + ty * 4;
    const int n0 = bn + tx * 4;

    if constexpr (MODE == 0) {
        float* C = (float*)Cout;
#pragma unroll
        for (int i = 0; i < 4; ++i) {
            const float4 v = make_float4(acc[i][0] + bias[n0 + 0], acc[i][1] + bias[n0 + 1],
                                         acc[i][2] + bias[n0 + 2], acc[i][3] + bias[n0 + 3]);
            *(float4*)&C[(size_t)(m0 + i) * DD + n0] = v;
        }
    } else if constexpr (MODE == 1 || MODE == 2) {
        unsigned short* C = (unsigned short*)Cout;
        const int h_ = n0 >> 5;
        const int d_ = n0 & 31;
#pragma unroll
        for (int i = 0; i < 4; ++i) {
            const int m = m0 + i;
            const int b_ = m >> 11;
            const int l_ = m & (LL - 1);
            float v[4];
#pragma unroll
            for (int j = 0; j < 4; ++j) {
                v[j] = acc[i][j] + bias[n0 + j];
                if (MODE == 1) v[j] *= SCALE;
            }
            const unsigned lo = f2bf(v[0]) | (f2bf(v[1]) << 16);
            const unsigned hi = f2bf(v[2]) | (f2bf(v[3]) << 16);
            *(uint2*)&C[(((size_t)b_ * HH + h_) * LL + l_) * HDIM + d_] = make_uint2(lo, hi);
        }
    } else {  // MODE 3: V^T [B,H,32,L]
        unsigned short* C = (unsigned short*)Cout;
        const int b_ = bm >> 11;
        const int l0 = (bm & (LL - 1)) + ty * 4;
#pragma unroll
        for (int j = 0; j < 4; ++j) {
            const int n = n0 + j;
            const int h_ = n >> 5;
            const int d_ = n & 31;
            const float bj = bias[n];
            const unsigned lo = f2bf(acc[0][j] + bj) | (f2bf(acc[1][j] + bj) << 16);
            const unsigned hi = f2bf(acc[2][j] + bj) | (f2bf(acc[3][j] + bj) << 16);
            *(uint2*)&C[(((size_t)b_ * HH + h_) * HDIM + d_) * LL + l0] = make_uint2(lo, hi);
        }
    }
}

// ---------------------------------------------------------------------------
// MFMA bf16 causal flash attention.
// Block = 256 threads = 4 independent waves; wave w owns q-rows
// [qblk*64 + w*16, +16). KV-block = 64 keys/iter.
// S^T = mfma(K, Q) so each lane holds one q-row's 16-key slice in-register
// (softmax = in-lane reduce + 2 shfl_xor). P -> LDS (b64 writes) -> A-frags.
// The P write->read is same-wave cross-lane: ordering pinned by the
// s_waitcnt lgkmcnt(0) + sched_barrier(0) fence (no __syncthreads needed).
// V read as B-frags straight from global V^T [B,H,32,L] (L2-resident).
// Output written normalized to yb [B,L,256] f32.
// ---------------------------------------------------------------------------
__global__ __launch_bounds__(256) void attn_mfma(const unsigned short* __restrict__ qb,
                                                 const unsigned short* __restrict__ kb,
                                                 const unsigned short* __restrict__ vt,
                                                 float* __restrict__ yb) {
    __shared__ unsigned short plds[4][16][72];  // [wave][q-row][64 keys + 8 pad]
    const int tid = threadIdx.x;
    const int w = tid >> 6;
    const int lane = tid & 63;
    const int g = lane >> 4;   // 0..3
    const int c = lane & 15;   // 0..15
    const int qblk = (int)(gridDim.x - 1 - blockIdx.x);  // longest-first
    const int bh = blockIdx.y;
    const int qrow0 = qblk * 64 + w * 16;

    const unsigned short* Qp = qb + (size_t)bh * LL * HDIM;
    const unsigned short* Kp = kb + (size_t)bh * LL * HDIM;
    const unsigned short* Vp = vt + (size_t)bh * HDIM * LL;

    // Q fragment (doubles as MFMA B-operand): lane holds Q[qrow0+c][g*8..+7]
    const short8 qf = *(const short8*)(Qp + (size_t)(qrow0 + c) * HDIM + g * 8);

    f32x4 y0 = {0.f, 0.f, 0.f, 0.f};  // y[q=4g+r][d=c]
    f32x4 y1 = {0.f, 0.f, 0.f, 0.f};  // y[q=4g+r][d=16+c]
    float mrun = -1e30f, lsum = 0.f;

    auto step = [&](int kt, bool masked) {
        const f32x4 z = {0.f, 0.f, 0.f, 0.f};
        f32x4 st[4];
        // S^T tiles: st[t][r] = S[key=kt+16t+4g+r][q=c]  (Q pre-scaled)
#pragma unroll
        for (int t = 0; t < 4; ++t) {
            const short8 kf = *(const short8*)(Kp + (size_t)(kt + 16 * t + c) * HDIM + g * 8);
            st[t] = __builtin_amdgcn_mfma_f32_16x16x32_bf16(kf, qf, z, 0, 0, 0);
        }
        if (masked) {
#pragma unroll
            for (int t = 0; t < 4; ++t)
#pragma unroll
                for (int r = 0; r < 4; ++r)
                    if (kt + 16 * t + 4 * g + r > qrow0 + c) st[t][r] = -1e30f;
        }
        // online softmax for row q=c (16 in-lane keys + reduce over g)
        float pm = -1e30f;
#pragma unroll
        for (int t = 0; t < 4; ++t)
#pragma unroll
            for (int r = 0; r < 4; ++r) pm = fmaxf(pm, st[t][r]);
        pm = fmaxf(pm, __shfl_xor(pm, 16));
        pm = fmaxf(pm, __shfl_xor(pm, 32));
        const float mnew = fmaxf(mrun, pm);
        const float corr = __expf(mrun - mnew);
        mrun = mnew;
        float ps = 0.f;
#pragma unroll
        for (int t = 0; t < 4; ++t) {
            const float p0 = __expf(st[t][0] - mnew);
            const float p1 = __expf(st[t][1] - mnew);
            const float p2 = __expf(st[t][2] - mnew);
            const float p3 = __expf(st[t][3] - mnew);
            ps += (p0 + p1) + (p2 + p3);
            const unsigned lo = f2bf(p0) | (f2bf(p1) << 16);
            const unsigned hi = f2bf(p2) | (f2bf(p3) << 16);
            // P[q=c][key=16t+4g..+3], contiguous 4 bf16 -> one b64 write
            *(uint2*)&plds[w][c][16 * t + 4 * g] = make_uint2(lo, hi);
        }
        ps += __shfl_xor(ps, 16);
        ps += __shfl_xor(ps, 32);
        lsum = lsum * corr + ps;
        // rescale y accumulators (row of y-frag = q 4g+r; corr lives at lane c==q)
#pragma unroll
        for (int r = 0; r < 4; ++r) {
            const float cr = __shfl(corr, (lane & 48) | (4 * g + r));
            y0[r] *= cr;
            y1[r] *= cr;
        }
        // Fence: stores can't sink below (memory clobber), HW drains ds_writes
        // (lgkmcnt(0)), scheduler can't hoist the dependent reads/MFMAs above.
        asm volatile("s_waitcnt lgkmcnt(0)" ::: "memory");
        __builtin_amdgcn_sched_barrier(0);
        // PV: A = P[16q x 32k chunks], B = V^T-sourced fragments
        const unsigned short* prow = &plds[w][c][0];
        const short8 pa0 = *(const short8*)(prow + g * 8);
        const short8 pa1 = *(const short8*)(prow + 32 + g * 8);
        const short8 v00 = *(const short8*)(Vp + (size_t)c * LL + kt + g * 8);
        const short8 v10 = *(const short8*)(Vp + (size_t)c * LL + kt + 32 + g * 8);
        const short8 v01 = *(const short8*)(Vp + (size_t)(16 + c) * LL + kt + g * 8);
        const short8 v11 = *(const short8*)(Vp + (size_t)(16 + c) * LL + kt + 32 + g * 8);
        y0 = __builtin_amdgcn_mfma_f32_16x16x32_bf16(pa0, v00, y0, 0, 0, 0);
        y0 = __builtin_amdgcn_mfma_f32_16x16x32_bf16(pa1, v10, y0, 0, 0, 0);
        y1 = __builtin_amdgcn_mfma_f32_16x16x32_bf16(pa0, v01, y1, 0, 0, 0);
        y1 = __builtin_amdgcn_mfma_f32_16x16x32_bf16(pa1, v11, y1, 0, 0, 0);
    };

    for (int kt = 0; kt < qblk * 64; kt += 64) step(kt, false);
    step(qblk * 64, true);  // diagonal tile, causal-masked

    // normalize + write y in [B, L, 256] f32
#pragma unroll
    for (int r = 0; r < 4; ++r) {
        const float ls = __shfl(lsum, (lane & 48) | (4 * g + r));
        const float inv = 1.f / ls;
        float* yrow = yb + ((size_t)(bh >> 3) * LL + qrow0 + 4 * g + r) * DD + (bh & 7) * HDIM;
        yrow[c] = y0[r] * inv;
        yrow[16 + c] = y1[r] * inv;
    }
}

// ---------------------------------------------------------------------------
extern "C" void kernel_launch(void* const* d_in, const int* in_sizes, int n_in,
                              void* d_out, int out_size, void* d_ws, size_t ws_size,
                              hipStream_t stream) {
    const float* key   = (const float*)d_in[0];
    const float* value = (const float*)d_in[1];
    const float* query = (const float*)d_in[2];
    const float* Wk = (const float*)d_in[3];
    const float* bk = (const float*)d_in[4];
    const float* Wq = (const float*)d_in[5];
    const float* bq = (const float*)d_in[6];
    const float* Wv = (const float*)d_in[7];
    const float* bv = (const float*)d_in[8];
    const float* Wp = (const float*)d_in[9];
    const float* bp = (const float*)d_in[10];
    float* out = (float*)d_out;

    const size_t SZ = (size_t)BHT * LL * HDIM;  // 2,097,152 elems per tensor
    unsigned short* qb16 = (unsigned short*)d_ws;   // [B,H,L,32] bf16 (scaled)
    unsigned short* kb16 = qb16 + SZ;               // [B,H,L,32] bf16
    unsigned short* vt16 = kb16 + SZ;               // [B,H,32,L] bf16
    float* yb = (float*)(vt16 + SZ);                // [B,L,256] f32

    const dim3 gg(MTOT / 64, DD / 64);
    gemm_xwT<1><<<gg, 256, 0, stream>>>(query, Wq, bq, qb16);
    gemm_xwT<2><<<gg, 256, 0, stream>>>(key,   Wk, bk, kb16);
    gemm_xwT<3><<<gg, 256, 0, stream>>>(value, Wv, bv, vt16);
    attn_mfma<<<dim3(LL / 64, BHT), 256, 0, stream>>>(qb16, kb16, vt16, yb);
    gemm_xwT<0><<<gg, 256, 0, stream>>>(yb, Wp, bp, out);
}